// Round 7
// baseline (167.628 us; speedup 1.0000x reference)
//
#include <hip/hip_runtime.h>
#include <hip/hip_bf16.h>

#define NPOS 1600
#define HEADS 8
#define KEY_DIM 16
#define HEAD_DIM 32
#define DIM 256
#define QKV_DIM 512
#define RSEL 320   // ascending 0-based order-stat index (num_keep = 1280)
#define QBLK 8
#define NBINS 256

typedef __attribute__((ext_vector_type(8))) short short8;
typedef __attribute__((ext_vector_type(4))) float f32x4;

__device__ __forceinline__ unsigned short f2b(float f) {
  unsigned u = __float_as_uint(f);
  unsigned r = u + 0x7FFFu + ((u >> 16) & 1u);
  return (unsigned short)(r >> 16);
}
__device__ __forceinline__ float b2f(unsigned short h) {
  return __uint_as_float(((unsigned)h) << 16);
}

// ---------------- kernel A: transpose x -> xT bf16 [b][n][c] ----------------
__global__ __launch_bounds__(256) void xpose_kernel(
    const float* __restrict__ x, unsigned short* __restrict__ xT16) {
  __shared__ float tile[64][65];
  int t = threadIdx.x;
  int n0 = blockIdx.x * 64, c0 = blockIdx.y * 64, b = blockIdx.z;
  for (int r = 0; r < 16; ++r) {
    int idx = r * 256 + t;
    int row = idx >> 6, col = idx & 63;
    tile[row][col] = x[((size_t)(b * DIM + c0 + row)) * NPOS + n0 + col];
  }
  __syncthreads();
  int nl = t >> 2, cc = (t & 3) * 16;
  short8 o0, o1;
  #pragma unroll
  for (int i = 0; i < 8; ++i) o0[i] = (short)f2b(tile[cc + i][nl]);
  #pragma unroll
  for (int i = 0; i < 8; ++i) o1[i] = (short)f2b(tile[cc + 8 + i][nl]);
  size_t base = ((size_t)(b * NPOS + n0 + nl)) * DIM + c0 + cc;
  *(short8*)(xT16 + base) = o0;
  *(short8*)(xT16 + base + 8) = o1;
}

// ---------------- kernel B: convert weights to bf16 ----------------
__global__ __launch_bounds__(256) void convw_kernel(
    const float* __restrict__ wq, const float* __restrict__ wp,
    unsigned short* __restrict__ wqb, unsigned short* __restrict__ wpb) {
  int idx = (blockIdx.x * 256 + threadIdx.x) * 8;
  #pragma unroll
  for (int i = 0; i < 8; ++i) {
    int e = idx + i;
    if (e < QKV_DIM * DIM) wqb[e] = f2b(wq[e]);
    else wpb[e - QKV_DIM * DIM] = f2b(wp[e - QKV_DIM * DIM]);
  }
}

// ---------------- kernel 1: qkv via MFMA ----------------
__global__ __launch_bounds__(256) void qkv_mfma(
    const unsigned short* __restrict__ xT16, const unsigned short* __restrict__ wqb,
    const float* __restrict__ bq, float* __restrict__ qbuf,
    float* __restrict__ kbuf, unsigned short* __restrict__ vb16) {
  int t = threadIdx.x, lane = t & 63, w = t >> 6;
  int l15 = lane & 15, lg = lane >> 4;
  int n0 = blockIdx.x * 64, co0 = blockIdx.y * 64, b = blockIdx.z;
  int cow = co0 + w * 16;
  short8 af[8];
  #pragma unroll
  for (int ks = 0; ks < 8; ++ks)
    af[ks] = *(const short8*)(wqb + (size_t)(cow + l15) * DIM + ks * 32 + lg * 8);
  f32x4 acc[4];
  #pragma unroll
  for (int sub = 0; sub < 4; ++sub) {
    int n = n0 + sub * 16 + l15;
    const unsigned short* xb = xT16 + (size_t)(b * NPOS + n) * DIM + lg * 8;
    f32x4 a = {0.f, 0.f, 0.f, 0.f};
    #pragma unroll
    for (int ks = 0; ks < 8; ++ks)
      a = __builtin_amdgcn_mfma_f32_16x16x32_bf16(af[ks], *(const short8*)(xb + ks * 32), a, 0, 0, 0);
    acc[sub] = a;
  }
  #pragma unroll
  for (int sub = 0; sub < 4; ++sub) {
    #pragma unroll
    for (int r = 0; r < 4; ++r) {
      int co = cow + lg * 4 + r;
      int n = n0 + sub * 16 + l15;
      float val = acc[sub][r] + bq[co];
      int hh = co >> 6, rr = co & 63;
      if (rr < KEY_DIM)
        qbuf[((b * HEADS + hh) * KEY_DIM + rr) * NPOS + n] = val;
      else if (rr < 2 * KEY_DIM)
        kbuf[((b * HEADS + hh) * KEY_DIM + (rr - KEY_DIM)) * NPOS + n] = val;
      else
        vb16[((size_t)(b * DIM + hh * HEAD_DIM + (rr - 2 * KEY_DIM))) * NPOS + n] = f2b(val);
    }
  }
}

// ---------------- kernel 2: L2-normalize q,k + emit bf16 transposed [bh][n][kk] ----------------
__global__ __launch_bounds__(256) void norm_kernel(
    const float* __restrict__ qbuf, const float* __restrict__ kbuf,
    unsigned short* __restrict__ qT16, unsigned short* __restrict__ kT16) {
  __shared__ float invn[16];
  __shared__ float tile[16][260];
  int bh = blockIdx.x;
  const float* src = blockIdx.y ? kbuf : qbuf;
  unsigned short* dst = blockIdx.y ? kT16 : qT16;
  const float* rows = src + (size_t)bh * 16 * NPOS;
  int t = threadIdx.x;
  int r = t >> 4, s = t & 15;
  float ss = 0.0f;
  for (int j = 0; j < 100; ++j) {
    float v = rows[r * NPOS + s + 16 * j];
    ss += v * v;
  }
  #pragma unroll
  for (int o = 8; o; o >>= 1) ss += __shfl_xor(ss, o, 64);
  if (s == 0) invn[r] = 1.0f / fmaxf(sqrtf(ss), 1e-12f);
  __syncthreads();
  float iv[16];
  #pragma unroll
  for (int kk = 0; kk < 16; ++kk) iv[kk] = invn[kk];
  for (int ch = 0; ch < 7; ++ch) {
    int m = ch * 256 + t;
    __syncthreads();
    if (m < NPOS)
      for (int kk = 0; kk < 16; ++kk) tile[kk][t] = rows[kk * NPOS + m];
    __syncthreads();
    if (m < NPOS) {
      short8 o0, o1;
      #pragma unroll
      for (int i = 0; i < 8; ++i) o0[i] = (short)f2b(tile[i][t] * iv[i]);
      #pragma unroll
      for (int i = 0; i < 8; ++i) o1[i] = (short)f2b(tile[8 + i][t] * iv[8 + i]);
      size_t base = ((size_t)bh * NPOS + m) * KEY_DIM;
      *(short8*)(dst + base) = o0;
      *(short8*)(dst + base + 8) = o1;
    }
  }
}

// ---------------- kernel 3: fused attention, MFMA, QBLK=8, 4 waves ----------------
__global__ __launch_bounds__(256) void attn_kernel(
    const unsigned short* __restrict__ qT16, const unsigned short* __restrict__ kT16,
    const unsigned short* __restrict__ vb16, const float* __restrict__ temp,
    const float* __restrict__ supp, const float* __restrict__ wpe,
    const float* __restrict__ bpe, unsigned short* __restrict__ ybT) {
  __shared__ __align__(128) unsigned short s16[QBLK * NPOS];  // 25600 B
  __shared__ unsigned hred[4][NBINS];                         // 4096 B (hist, then PV partials)
  __shared__ float invs[QBLK];
  int t = threadIdx.x, lane = t & 63, w = t >> 6;
  int l15 = lane & 15, lg = lane >> 4;
  int n0 = blockIdx.x * QBLK;
  int h = blockIdx.y, b = blockIdx.z;
  int bh = b * HEADS + h;
  float tscale = temp[h];
  float sgm = 1.0f / (1.0f + __expf(-supp[0]));

  // A-frag: Q tile rows n0..n0+7 (rows 8..15 zero)
  short8 qa = {0, 0, 0, 0, 0, 0, 0, 0};
  if (lane < 32 && l15 < QBLK)
    qa = *(const short8*)(qT16 + ((size_t)bh * NPOS + n0 + l15) * KEY_DIM + lg * 8);

  // ---- QK^T: 100 m-tiles across 4 waves ----
  for (int mt = w; mt < NPOS / 16; mt += 4) {
    int m0 = mt * 16;
    short8 kb = {0, 0, 0, 0, 0, 0, 0, 0};
    if (lane < 32)
      kb = *(const short8*)(kT16 + ((size_t)bh * NPOS + m0 + l15) * KEY_DIM + lg * 8);
    f32x4 acc = {0.f, 0.f, 0.f, 0.f};
    acc = __builtin_amdgcn_mfma_f32_16x16x32_bf16(qa, kb, acc, 0, 0, 0);
    #pragma unroll
    for (int r = 0; r < 4; ++r) {
      int row = lg * 4 + r;
      if (row < QBLK) {
        int byteoff = (row * 3200 + (m0 + l15) * 2) ^ ((row & 7) << 4);
        s16[byteoff >> 1] = f2b(acc[r] * tscale);
      }
    }
  }
  __syncthreads();

  // ---- per-wave select + softmax: wave w owns rows 2w, 2w+1 ----
  for (int rl = 0; rl < 2; ++rl) {
    int rr = w * 2 + rl;
    int rbase = rr * 3200, xr = (rr & 7) << 4;
    float sv[25];
    float mn = 3.4e38f, mx = -3.4e38f;
    #pragma unroll
    for (int k = 0; k < 25; ++k) {
      int byteoff = rbase + (((lane + 64 * k) * 2) ^ xr);
      float v = b2f(s16[byteoff >> 1]);
      sv[k] = v; mn = fminf(mn, v); mx = fmaxf(mx, v);
    }
    #pragma unroll
    for (int k4 = 0; k4 < 4; ++k4) hred[w][lane * 4 + k4] = 0;
    #pragma unroll
    for (int o = 32; o; o >>= 1) {
      mn = fminf(mn, __shfl_xor(mn, o, 64));
      mx = fmaxf(mx, __shfl_xor(mx, o, 64));
    }
    float range = fmaxf(mx - mn, 1e-30f) * 1.000001f;
    float invw = (float)NBINS / range;
    #pragma unroll
    for (int k = 0; k < 25; ++k) {
      int idx = (int)((sv[k] - mn) * invw);
      idx = idx < 0 ? 0 : (idx > NBINS - 1 ? NBINS - 1 : idx);
      atomicAdd(&hred[w][idx], 1u);
    }
    int h0 = (int)hred[w][4 * lane], h1 = (int)hred[w][4 * lane + 1];
    int h2 = (int)hred[w][4 * lane + 2], h3 = (int)hred[w][4 * lane + 3];
    int lsum = h0 + h1 + h2 + h3;
    int incl = lsum;
    #pragma unroll
    for (int o = 1; o < 64; o <<= 1) {
      int xx = __shfl_up(incl, o, 64);
      if (lane >= o) incl += xx;
    }
    int c = incl - lsum;
    int cand = 1 << 30;
    if (c <= RSEL && c + h0 > RSEL) cand = 4 * lane;
    c += h0; if (c <= RSEL && c + h1 > RSEL) cand = 4 * lane + 1;
    c += h1; if (c <= RSEL && c + h2 > RSEL) cand = 4 * lane + 2;
    c += h2; if (c <= RSEL && c + h3 > RSEL) cand = 4 * lane + 3;
    #pragma unroll
    for (int o = 32; o; o >>= 1) cand = min(cand, __shfl_xor(cand, o, 64));
    float thr = mn + (float)cand * (range / (float)NBINS);

    float lmax = -3.4e38f;
    #pragma unroll
    for (int k = 0; k < 25; ++k) {
      float p = sv[k] * (sv[k] >= thr ? 1.0f : sgm);
      sv[k] = p;
      lmax = fmaxf(lmax, p);
    }
    #pragma unroll
    for (int o = 32; o; o >>= 1) lmax = fmaxf(lmax, __shfl_xor(lmax, o, 64));
    float lsumf = 0.0f;
    #pragma unroll
    for (int k = 0; k < 25; ++k) {
      float e = __expf(sv[k] - lmax);
      lsumf += e;
      int byteoff = rbase + (((lane + 64 * k) * 2) ^ xr);
      s16[byteoff >> 1] = f2b(e);
    }
    #pragma unroll
    for (int o = 32; o; o >>= 1) lsumf += __shfl_xor(lsumf, o, 64);
    if (lane == 0) invs[rr] = 1.0f / lsumf;
  }
  __syncthreads();

  // ---- PV: wave w -> d-tile (w&1), m-half (w>>1) ----
  float* red = (float*)hred[w];
  int tile = w & 1, d0 = tile * 16;
  const unsigned short* vrow = vb16 + ((size_t)(b * DIM + h * HEAD_DIM + d0 + l15)) * NPOS;
  f32x4 acc = {0.f, 0.f, 0.f, 0.f};
  for (int c = (w >> 1); c < NPOS / 32; c += 2) {
    int m0 = c * 32 + lg * 8;
    short8 va = *(const short8*)(vrow + m0);
    short8 pb = {0, 0, 0, 0, 0, 0, 0, 0};
    if (l15 < QBLK) {
      int byteoff = (l15 * 3200 + m0 * 2) ^ ((l15 & 7) << 4);
      pb = *(const short8*)(s16 + (byteoff >> 1));
    }
    acc = __builtin_amdgcn_mfma_f32_16x16x32_bf16(va, pb, acc, 0, 0, 0);
  }
  #pragma unroll
  for (int r = 0; r < 4; ++r) red[(lg * 4 + r) * 16 + l15] = acc[r];
  __syncthreads();

  // ---- epilogue: cross-wave reduce + normalize + fused pe conv + bf16 store ----
  {
    int d = t >> 3, j = t & 7;       // d 0..31, j 0..7
    int tl = d >> 4, i = d & 15;
    int p = i * 16 + j;
    float v = ((float*)hred[tl])[p] + ((float*)hred[tl + 2])[p];
    int c = h * HEAD_DIM + d;
    int n = n0 + j;
    float o = v * invs[j];
    int py = n / 40, px = n - py * 40;
    const unsigned short* vp = vb16 + (size_t)(b * DIM + c) * NPOS;
    const float* w9 = wpe + c * 9;
    float acc2 = bpe[c];
    #pragma unroll
    for (int dy = -1; dy <= 1; ++dy) {
      int iy = py + dy;
      if (iy < 0 || iy > 39) continue;
      #pragma unroll
      for (int dx = -1; dx <= 1; ++dx) {
        int ix = px + dx;
        if (ix < 0 || ix > 39) continue;
        acc2 = fmaf(b2f(vp[iy * 40 + ix]), w9[(dy + 1) * 3 + (dx + 1)], acc2);
      }
    }
    o += acc2;
    ybT[((size_t)(b * NPOS + n)) * DIM + c] = f2b(o);
  }
}

// ---------------- kernel 5: proj via MFMA -> fp32 out ----------------
__global__ __launch_bounds__(256) void proj_mfma(
    const unsigned short* __restrict__ ybT, const unsigned short* __restrict__ wpb,
    const float* __restrict__ bp, float* __restrict__ out) {
  int t = threadIdx.x, lane = t & 63, w = t >> 6;
  int l15 = lane & 15, lg = lane >> 4;
  int n0 = blockIdx.x * 64, co0 = blockIdx.y * 64, b = blockIdx.z;
  int cow = co0 + w * 16;
  short8 af[8];
  #pragma unroll
  for (int ks = 0; ks < 8; ++ks)
    af[ks] = *(const short8*)(wpb + (size_t)(cow + l15) * DIM + ks * 32 + lg * 8);
  f32x4 acc[4];
  #pragma unroll
  for (int sub = 0; sub < 4; ++sub) {
    int n = n0 + sub * 16 + l15;
    const unsigned short* yb = ybT + (size_t)(b * NPOS + n) * DIM + lg * 8;
    f32x4 a = {0.f, 0.f, 0.f, 0.f};
    #pragma unroll
    for (int ks = 0; ks < 8; ++ks)
      a = __builtin_amdgcn_mfma_f32_16x16x32_bf16(af[ks], *(const short8*)(yb + ks * 32), a, 0, 0, 0);
    acc[sub] = a;
  }
  #pragma unroll
  for (int sub = 0; sub < 4; ++sub) {
    #pragma unroll
    for (int r = 0; r < 4; ++r) {
      int co = cow + lg * 4 + r;
      int n = n0 + sub * 16 + l15;
      out[((size_t)(b * DIM + co)) * NPOS + n] = acc[sub][r] + bp[co];
    }
  }
}

extern "C" void kernel_launch(void* const* d_in, const int* in_sizes, int n_in,
                              void* d_out, int out_size, void* d_ws, size_t ws_size,
                              hipStream_t stream) {
  (void)in_sizes; (void)n_in; (void)out_size; (void)ws_size;
  const float* x = (const float*)d_in[0];
  const float* w_qkv = (const float*)d_in[1];
  const float* b_qkv = (const float*)d_in[2];
  const float* w_proj = (const float*)d_in[3];
  const float* b_proj = (const float*)d_in[4];
  const float* w_pe = (const float*)d_in[5];
  const float* b_pe = (const float*)d_in[6];
  const float* temperature = (const float*)d_in[7];
  const float* supp = (const float*)d_in[8];

  float* wsf = (float*)d_ws;
  float* qbuf = wsf;                                    // 409600 f
  float* kbuf = qbuf + 409600;                          // 409600 f
  unsigned short* vb16 = (unsigned short*)(kbuf + 409600);  // 819200 bf16
  unsigned short* qT16 = vb16 + 819200;                 // 409600
  unsigned short* kT16 = qT16 + 409600;                 // 409600
  unsigned short* xT16 = kT16 + 409600;                 // 819200
  unsigned short* ybT  = xT16 + 819200;                 // 819200
  unsigned short* wqb  = ybT + 819200;                  // 131072
  unsigned short* wpb  = wqb + 131072;                  // 65536
  float* out = (float*)d_out;

  xpose_kernel<<<dim3(25, 4, 2), 256, 0, stream>>>(x, xT16);
  convw_kernel<<<dim3(96, 1, 1), 256, 0, stream>>>(w_qkv, w_proj, wqb, wpb);
  qkv_mfma<<<dim3(25, 8, 2), 256, 0, stream>>>(xT16, wqb, b_qkv, qbuf, kbuf, vb16);
  norm_kernel<<<dim3(16, 2), 256, 0, stream>>>(qbuf, kbuf, qT16, kT16);
  attn_kernel<<<dim3(NPOS / QBLK, HEADS, 2), 256, 0, stream>>>(qT16, kT16, vb16, temperature, supp, w_pe, b_pe, ybT);
  proj_mfma<<<dim3(25, 4, 2), 256, 0, stream>>>(ybT, wpb, b_proj, out);
}

// Round 9
// 157.879 us; speedup vs baseline: 1.0617x; 1.0617x over previous
//
#include <hip/hip_runtime.h>
#include <hip/hip_bf16.h>

#define NPOS 1600
#define HEADS 8
#define KEY_DIM 16
#define HEAD_DIM 32
#define DIM 256
#define QKV_DIM 512
#define RSEL 320   // ascending 0-based order-stat index (num_keep = 1280)
#define QBLK 16
#define NBINS 256

typedef __attribute__((ext_vector_type(8))) short short8;
typedef __attribute__((ext_vector_type(4))) float f32x4;
typedef __attribute__((ext_vector_type(4))) unsigned uint4v;

__device__ __forceinline__ unsigned short f2b(float f) {
  unsigned u = __float_as_uint(f);
  unsigned r = u + 0x7FFFu + ((u >> 16) & 1u);
  return (unsigned short)(r >> 16);
}
__device__ __forceinline__ float b2f(unsigned short h) {
  return __uint_as_float(((unsigned)h) << 16);
}
// bank-spread involution for the S tile (row stride 3200B, 128B-aligned base)
__device__ __forceinline__ int smask(int row) {
  return ((row & 7) << 4) ^ ((row & 12) << 3);
}

// ---------------- kernel A: transpose x -> xT bf16 [b][n][c] ----------------
__global__ __launch_bounds__(256) void xpose_kernel(
    const float* __restrict__ x, unsigned short* __restrict__ xT16) {
  __shared__ float tile[64][65];
  int t = threadIdx.x;
  int n0 = blockIdx.x * 64, c0 = blockIdx.y * 64, b = blockIdx.z;
  for (int r = 0; r < 16; ++r) {
    int idx = r * 256 + t;
    int row = idx >> 6, col = idx & 63;
    tile[row][col] = x[((size_t)(b * DIM + c0 + row)) * NPOS + n0 + col];
  }
  __syncthreads();
  int nl = t >> 2, cc = (t & 3) * 16;
  short8 o0, o1;
  #pragma unroll
  for (int i = 0; i < 8; ++i) o0[i] = (short)f2b(tile[cc + i][nl]);
  #pragma unroll
  for (int i = 0; i < 8; ++i) o1[i] = (short)f2b(tile[cc + 8 + i][nl]);
  size_t base = ((size_t)(b * NPOS + n0 + nl)) * DIM + c0 + cc;
  *(short8*)(xT16 + base) = o0;
  *(short8*)(xT16 + base + 8) = o1;
}

// ---------------- kernel B: convert weights to bf16 ----------------
__global__ __launch_bounds__(256) void convw_kernel(
    const float* __restrict__ wq, const float* __restrict__ wp,
    unsigned short* __restrict__ wqb, unsigned short* __restrict__ wpb) {
  int idx = (blockIdx.x * 256 + threadIdx.x) * 8;
  #pragma unroll
  for (int i = 0; i < 8; ++i) {
    int e = idx + i;
    if (e < QKV_DIM * DIM) wqb[e] = f2b(wq[e]);
    else wpb[e - QKV_DIM * DIM] = f2b(wp[e - QKV_DIM * DIM]);
  }
}

// ---------------- kernel 1: qkv via MFMA ----------------
__global__ __launch_bounds__(256) void qkv_mfma(
    const unsigned short* __restrict__ xT16, const unsigned short* __restrict__ wqb,
    const float* __restrict__ bq, float* __restrict__ qbuf,
    float* __restrict__ kbuf, unsigned short* __restrict__ vb16) {
  int t = threadIdx.x, lane = t & 63, w = t >> 6;
  int l15 = lane & 15, lg = lane >> 4;
  int n0 = blockIdx.x * 64, co0 = blockIdx.y * 64, b = blockIdx.z;
  int cow = co0 + w * 16;
  short8 af[8];
  #pragma unroll
  for (int ks = 0; ks < 8; ++ks)
    af[ks] = *(const short8*)(wqb + (size_t)(cow + l15) * DIM + ks * 32 + lg * 8);
  f32x4 acc[4];
  #pragma unroll
  for (int sub = 0; sub < 4; ++sub) {
    int n = n0 + sub * 16 + l15;
    const unsigned short* xb = xT16 + (size_t)(b * NPOS + n) * DIM + lg * 8;
    f32x4 a = {0.f, 0.f, 0.f, 0.f};
    #pragma unroll
    for (int ks = 0; ks < 8; ++ks)
      a = __builtin_amdgcn_mfma_f32_16x16x32_bf16(af[ks], *(const short8*)(xb + ks * 32), a, 0, 0, 0);
    acc[sub] = a;
  }
  #pragma unroll
  for (int sub = 0; sub < 4; ++sub) {
    #pragma unroll
    for (int r = 0; r < 4; ++r) {
      int co = cow + lg * 4 + r;
      int n = n0 + sub * 16 + l15;
      float val = acc[sub][r] + bq[co];
      int hh = co >> 6, rr = co & 63;
      if (rr < KEY_DIM)
        qbuf[((b * HEADS + hh) * KEY_DIM + rr) * NPOS + n] = val;
      else if (rr < 2 * KEY_DIM)
        kbuf[((b * HEADS + hh) * KEY_DIM + (rr - KEY_DIM)) * NPOS + n] = val;
      else
        vb16[((size_t)(b * DIM + hh * HEAD_DIM + (rr - 2 * KEY_DIM))) * NPOS + n] = f2b(val);
    }
  }
}

// ---------------- kernel 2: L2-normalize q,k + emit bf16 transposed [bh][n][kk] ----------------
__global__ __launch_bounds__(256) void norm_kernel(
    const float* __restrict__ qbuf, const float* __restrict__ kbuf,
    unsigned short* __restrict__ qT16, unsigned short* __restrict__ kT16) {
  __shared__ float invn[16];
  __shared__ float tile[16][260];
  int bh = blockIdx.x;
  const float* src = blockIdx.y ? kbuf : qbuf;
  unsigned short* dst = blockIdx.y ? kT16 : qT16;
  const float* rows = src + (size_t)bh * 16 * NPOS;
  int t = threadIdx.x;
  int r = t >> 4, s = t & 15;
  float ss = 0.0f;
  for (int j = 0; j < 100; ++j) {
    float v = rows[r * NPOS + s + 16 * j];
    ss += v * v;
  }
  #pragma unroll
  for (int o = 8; o; o >>= 1) ss += __shfl_xor(ss, o, 64);
  if (s == 0) invn[r] = 1.0f / fmaxf(sqrtf(ss), 1e-12f);
  __syncthreads();
  float iv[16];
  #pragma unroll
  for (int kk = 0; kk < 16; ++kk) iv[kk] = invn[kk];
  for (int ch = 0; ch < 7; ++ch) {
    int m = ch * 256 + t;
    __syncthreads();
    if (m < NPOS)
      for (int kk = 0; kk < 16; ++kk) tile[kk][t] = rows[kk * NPOS + m];
    __syncthreads();
    if (m < NPOS) {
      short8 o0, o1;
      #pragma unroll
      for (int i = 0; i < 8; ++i) o0[i] = (short)f2b(tile[i][t] * iv[i]);
      #pragma unroll
      for (int i = 0; i < 8; ++i) o1[i] = (short)f2b(tile[8 + i][t] * iv[8 + i]);
      size_t base = ((size_t)bh * NPOS + m) * KEY_DIM;
      *(short8*)(dst + base) = o0;
      *(short8*)(dst + base + 8) = o1;
    }
  }
}

// ---------------- kernel 3: fused attention, MFMA, QBLK=16, 16 waves ----------------
__global__ __launch_bounds__(1024, 8) void attn_kernel(
    const unsigned short* __restrict__ qT16, const unsigned short* __restrict__ kT16,
    const unsigned short* __restrict__ vb16, const float* __restrict__ temp,
    const float* __restrict__ supp, const float* __restrict__ wpe,
    const float* __restrict__ bpe, unsigned short* __restrict__ ybT) {
  __shared__ __align__(128) unsigned short s16[QBLK * NPOS];  // 51200 B
  __shared__ unsigned hred[16][NBINS];                        // 16384 B (hist, then PV partials)
  __shared__ float invs[QBLK];
  int t = threadIdx.x, lane = t & 63, w = t >> 6;
  int l15 = lane & 15, lg = lane >> 4;
  int n0 = blockIdx.x * QBLK;
  int h = blockIdx.y, b = blockIdx.z;
  int bh = b * HEADS + h;
  float tscale = temp[h];
  float sgm = 1.0f / (1.0f + __expf(-supp[0]));

  // A-frag: Q tile (16 q-rows x K=32, kk>=16 zero via lanes>=32)
  {
    short8 qa = {0, 0, 0, 0, 0, 0, 0, 0};
    if (lane < 32)
      qa = *(const short8*)(qT16 + ((size_t)bh * NPOS + n0 + l15) * KEY_DIM + lg * 8);
    // ---- QK^T: 100 m-tiles across 16 waves ----
    for (int mt = w; mt < NPOS / 16; mt += 16) {
      int m0 = mt * 16;
      short8 kb = {0, 0, 0, 0, 0, 0, 0, 0};
      if (lane < 32)
        kb = *(const short8*)(kT16 + ((size_t)bh * NPOS + m0 + l15) * KEY_DIM + lg * 8);
      f32x4 acc = {0.f, 0.f, 0.f, 0.f};
      acc = __builtin_amdgcn_mfma_f32_16x16x32_bf16(qa, kb, acc, 0, 0, 0);
      #pragma unroll
      for (int r = 0; r < 4; ++r) {
        int row = lg * 4 + r;
        int byteoff = (row * 3200 + (m0 + l15) * 2) ^ smask(row);
        s16[byteoff >> 1] = f2b(acc[r] * tscale);
      }
    }
  }
  __syncthreads();

  // ---- per-wave select + softmax: wave w owns row w ----
  {
    int rbase = w * 3200, xr = smask(w);
    float sv[25];
    float mn = 3.4e38f, mx = -3.4e38f;
    #pragma unroll
    for (int k = 0; k < 25; ++k) {
      int byteoff = rbase + (((lane + 64 * k) * 2) ^ xr);
      float v = b2f(s16[byteoff >> 1]);
      sv[k] = v; mn = fminf(mn, v); mx = fmaxf(mx, v);
    }
    ((uint4v*)hred[w])[lane] = (uint4v){0, 0, 0, 0};
    #pragma unroll
    for (int o = 32; o; o >>= 1) {
      mn = fminf(mn, __shfl_xor(mn, o, 64));
      mx = fmaxf(mx, __shfl_xor(mx, o, 64));
    }
    float range = fmaxf(mx - mn, 1e-30f) * 1.000001f;
    float invw = (float)NBINS / range;
    #pragma unroll
    for (int k = 0; k < 25; ++k) {
      int idx = (int)((sv[k] - mn) * invw);
      idx = idx < 0 ? 0 : (idx > NBINS - 1 ? NBINS - 1 : idx);
      atomicAdd(&hred[w][idx], 1u);
    }
    int h0 = (int)hred[w][4 * lane], h1 = (int)hred[w][4 * lane + 1];
    int h2 = (int)hred[w][4 * lane + 2], h3 = (int)hred[w][4 * lane + 3];
    int lsum = h0 + h1 + h2 + h3;
    int incl = lsum;
    #pragma unroll
    for (int o = 1; o < 64; o <<= 1) {
      int xx = __shfl_up(incl, o, 64);
      if (lane >= o) incl += xx;
    }
    int c = incl - lsum;
    int cand = 1 << 30;
    if (c <= RSEL && c + h0 > RSEL) cand = 4 * lane;
    c += h0; if (c <= RSEL && c + h1 > RSEL) cand = 4 * lane + 1;
    c += h1; if (c <= RSEL && c + h2 > RSEL) cand = 4 * lane + 2;
    c += h2; if (c <= RSEL && c + h3 > RSEL) cand = 4 * lane + 3;
    #pragma unroll
    for (int o = 32; o; o >>= 1) cand = min(cand, __shfl_xor(cand, o, 64));
    float thr = mn + (float)cand * (range / (float)NBINS);

    float lmax = -3.4e38f;
    #pragma unroll
    for (int k = 0; k < 25; ++k) {
      float p = sv[k] * (sv[k] >= thr ? 1.0f : sgm);
      sv[k] = p;
      lmax = fmaxf(lmax, p);
    }
    #pragma unroll
    for (int o = 32; o; o >>= 1) lmax = fmaxf(lmax, __shfl_xor(lmax, o, 64));
    float lsumf = 0.0f;
    #pragma unroll
    for (int k = 0; k < 25; ++k) {
      float e = __expf(sv[k] - lmax);
      lsumf += e;
      int byteoff = rbase + (((lane + 64 * k) * 2) ^ xr);
      s16[byteoff >> 1] = f2b(e);
    }
    #pragma unroll
    for (int o = 32; o; o >>= 1) lsumf += __shfl_xor(lsumf, o, 64);
    if (lane == 0) invs[w] = 1.0f / lsumf;
  }
  __syncthreads();

  // ---- PV: wave w -> d-tile (w&1), m-split 8-way (w>>1) ----
  {
    float* red = (float*)hred[w];
    int tile = w & 1, d0 = tile * 16;
    const unsigned short* vrow = vb16 + ((size_t)(b * DIM + h * HEAD_DIM + d0 + l15)) * NPOS;
    f32x4 acc = {0.f, 0.f, 0.f, 0.f};
    for (int c = (w >> 1); c < NPOS / 32; c += 8) {
      int m0 = c * 32 + lg * 8;
      short8 va = *(const short8*)(vrow + m0);
      int byteoff = (l15 * 3200 + m0 * 2) ^ smask(l15);
      short8 pb = *(const short8*)(s16 + (byteoff >> 1));
      acc = __builtin_amdgcn_mfma_f32_16x16x32_bf16(va, pb, acc, 0, 0, 0);
    }
    #pragma unroll
    for (int r = 0; r < 4; ++r) red[(lg * 4 + r) * 16 + l15] = acc[r];
  }
  __syncthreads();

  // ---- epilogue: 8-way cross-wave reduce + normalize + fused pe conv + bf16 store ----
  if (t < 512) {
    int tl = t >> 8, i = (t >> 4) & 15, j = t & 15;
    int p = i * 16 + j;
    float v = 0.0f;
    #pragma unroll
    for (int s = 0; s < 8; ++s) v += ((float*)hred[tl + 2 * s])[p];
    int c = h * HEAD_DIM + tl * 16 + i;
    int n = n0 + j;
    float o = v * invs[j];
    int py = n / 40, px = n - py * 40;
    const unsigned short* vp = vb16 + (size_t)(b * DIM + c) * NPOS;
    const float* w9 = wpe + c * 9;
    float acc2 = bpe[c];
    #pragma unroll
    for (int dy = -1; dy <= 1; ++dy) {
      int iy = py + dy;
      if (iy < 0 || iy > 39) continue;
      #pragma unroll
      for (int dx = -1; dx <= 1; ++dx) {
        int ix = px + dx;
        if (ix < 0 || ix > 39) continue;
        acc2 = fmaf(b2f(vp[iy * 40 + ix]), w9[(dy + 1) * 3 + (dx + 1)], acc2);
      }
    }
    o += acc2;
    ybT[((size_t)(b * NPOS + n)) * DIM + c] = f2b(o);
  }
}

// ---------------- kernel 5: proj via MFMA -> fp32 out ----------------
__global__ __launch_bounds__(256) void proj_mfma(
    const unsigned short* __restrict__ ybT, const unsigned short* __restrict__ wpb,
    const float* __restrict__ bp, float* __restrict__ out) {
  int t = threadIdx.x, lane = t & 63, w = t >> 6;
  int l15 = lane & 15, lg = lane >> 4;
  int n0 = blockIdx.x * 64, co0 = blockIdx.y * 64, b = blockIdx.z;
  int cow = co0 + w * 16;
  short8 af[8];
  #pragma unroll
  for (int ks = 0; ks < 8; ++ks)
    af[ks] = *(const short8*)(wpb + (size_t)(cow + l15) * DIM + ks * 32 + lg * 8);
  f32x4 acc[4];
  #pragma unroll
  for (int sub = 0; sub < 4; ++sub) {
    int n = n0 + sub * 16 + l15;
    const unsigned short* yb = ybT + (size_t)(b * NPOS + n) * DIM + lg * 8;
    f32x4 a = {0.f, 0.f, 0.f, 0.f};
    #pragma unroll
    for (int ks = 0; ks < 8; ++ks)
      a = __builtin_amdgcn_mfma_f32_16x16x32_bf16(af[ks], *(const short8*)(yb + ks * 32), a, 0, 0, 0);
    acc[sub] = a;
  }
  #pragma unroll
  for (int sub = 0; sub < 4; ++sub) {
    #pragma unroll
    for (int r = 0; r < 4; ++r) {
      int co = cow + lg * 4 + r;
      int n = n0 + sub * 16 + l15;
      out[((size_t)(b * DIM + co)) * NPOS + n] = acc[sub][r] + bp[co];
    }
  }
}

extern "C" void kernel_launch(void* const* d_in, const int* in_sizes, int n_in,
                              void* d_out, int out_size, void* d_ws, size_t ws_size,
                              hipStream_t stream) {
  (void)in_sizes; (void)n_in; (void)out_size; (void)ws_size;
  const float* x = (const float*)d_in[0];
  const float* w_qkv = (const float*)d_in[1];
  const float* b_qkv = (const float*)d_in[2];
  const float* w_proj = (const float*)d_in[3];
  const float* b_proj = (const float*)d_in[4];
  const float* w_pe = (const float*)d_in[5];
  const float* b_pe = (const float*)d_in[6];
  const float* temperature = (const float*)d_in[7];
  const float* supp = (const float*)d_in[8];

  float* wsf = (float*)d_ws;
  float* qbuf = wsf;                                    // 409600 f
  float* kbuf = qbuf + 409600;                          // 409600 f
  unsigned short* vb16 = (unsigned short*)(kbuf + 409600);  // 819200 bf16
  unsigned short* qT16 = vb16 + 819200;                 // 409600
  unsigned short* kT16 = qT16 + 409600;                 // 409600
  unsigned short* xT16 = kT16 + 409600;                 // 819200
  unsigned short* ybT  = xT16 + 819200;                 // 819200
  unsigned short* wqb  = ybT + 819200;                  // 131072
  unsigned short* wpb  = wqb + 131072;                  // 65536
  float* out = (float*)d_out;

  xpose_kernel<<<dim3(25, 4, 2), 256, 0, stream>>>(x, xT16);
  convw_kernel<<<dim3(96, 1, 1), 256, 0, stream>>>(w_qkv, w_proj, wqb, wpb);
  qkv_mfma<<<dim3(25, 8, 2), 256, 0, stream>>>(xT16, wqb, b_qkv, qbuf, kbuf, vb16);
  norm_kernel<<<dim3(16, 2), 256, 0, stream>>>(qbuf, kbuf, qT16, kT16);
  attn_kernel<<<dim3(NPOS / QBLK, HEADS, 2), 1024, 0, stream>>>(qT16, kT16, vb16, temperature, supp, w_pe, b_pe, ybT);
  proj_mfma<<<dim3(25, 4, 2), 256, 0, stream>>>(ybT, wpb, b_proj, out);
}

// Round 10
// 111.095 us; speedup vs baseline: 1.5089x; 1.4211x over previous
//
#include <hip/hip_runtime.h>
#include <hip/hip_bf16.h>

#define NPOS 1600
#define HEADS 8
#define KEY_DIM 16
#define HEAD_DIM 32
#define DIM 256
#define QKV_DIM 512
#define RSEL 320   // ascending 0-based order-stat index (num_keep = 1280)
#define QBLK 16
#define NBINS 256

typedef __attribute__((ext_vector_type(8))) short short8;
typedef __attribute__((ext_vector_type(4))) float f32x4;
typedef __attribute__((ext_vector_type(4))) unsigned uint4v;

__device__ __forceinline__ unsigned short f2b(float f) {
  unsigned u = __float_as_uint(f);
  unsigned r = u + 0x7FFFu + ((u >> 16) & 1u);
  return (unsigned short)(r >> 16);
}
__device__ __forceinline__ float b2f(unsigned short h) {
  return __uint_as_float(((unsigned)h) << 16);
}
// bank-spread involution for the S tile (row stride 3200B, 128B-aligned base):
// spreads the 4 QK^T-write row-groups across all 32 banks; select reads stay a
// within-128B permutation; PV b128 reads become 2-way (free).
__device__ __forceinline__ int smask(int row) {
  return ((row & 7) << 4) ^ ((row & 12) << 3);
}

// ---------------- kernel A: transpose x -> xT bf16 [b][n][c] ----------------
__global__ __launch_bounds__(256) void xpose_kernel(
    const float* __restrict__ x, unsigned short* __restrict__ xT16) {
  __shared__ float tile[64][65];
  int t = threadIdx.x;
  int n0 = blockIdx.x * 64, c0 = blockIdx.y * 64, b = blockIdx.z;
  for (int r = 0; r < 16; ++r) {
    int idx = r * 256 + t;
    int row = idx >> 6, col = idx & 63;
    tile[row][col] = x[((size_t)(b * DIM + c0 + row)) * NPOS + n0 + col];
  }
  __syncthreads();
  int nl = t >> 2, cc = (t & 3) * 16;
  short8 o0, o1;
  #pragma unroll
  for (int i = 0; i < 8; ++i) o0[i] = (short)f2b(tile[cc + i][nl]);
  #pragma unroll
  for (int i = 0; i < 8; ++i) o1[i] = (short)f2b(tile[cc + 8 + i][nl]);
  size_t base = ((size_t)(b * NPOS + n0 + nl)) * DIM + c0 + cc;
  *(short8*)(xT16 + base) = o0;
  *(short8*)(xT16 + base + 8) = o1;
}

// ---------------- kernel B: convert weights to bf16 ----------------
__global__ __launch_bounds__(256) void convw_kernel(
    const float* __restrict__ wq, const float* __restrict__ wp,
    unsigned short* __restrict__ wqb, unsigned short* __restrict__ wpb) {
  int idx = (blockIdx.x * 256 + threadIdx.x) * 8;
  #pragma unroll
  for (int i = 0; i < 8; ++i) {
    int e = idx + i;
    if (e < QKV_DIM * DIM) wqb[e] = f2b(wq[e]);
    else wpb[e - QKV_DIM * DIM] = f2b(wp[e - QKV_DIM * DIM]);
  }
}

// ---------------- kernel 1: qkv via MFMA ----------------
__global__ __launch_bounds__(256) void qkv_mfma(
    const unsigned short* __restrict__ xT16, const unsigned short* __restrict__ wqb,
    const float* __restrict__ bq, float* __restrict__ qbuf,
    float* __restrict__ kbuf, unsigned short* __restrict__ vb16) {
  int t = threadIdx.x, lane = t & 63, w = t >> 6;
  int l15 = lane & 15, lg = lane >> 4;
  int n0 = blockIdx.x * 64, co0 = blockIdx.y * 64, b = blockIdx.z;
  int cow = co0 + w * 16;
  short8 af[8];
  #pragma unroll
  for (int ks = 0; ks < 8; ++ks)
    af[ks] = *(const short8*)(wqb + (size_t)(cow + l15) * DIM + ks * 32 + lg * 8);
  f32x4 acc[4];
  #pragma unroll
  for (int sub = 0; sub < 4; ++sub) {
    int n = n0 + sub * 16 + l15;
    const unsigned short* xb = xT16 + (size_t)(b * NPOS + n) * DIM + lg * 8;
    f32x4 a = {0.f, 0.f, 0.f, 0.f};
    #pragma unroll
    for (int ks = 0; ks < 8; ++ks)
      a = __builtin_amdgcn_mfma_f32_16x16x32_bf16(af[ks], *(const short8*)(xb + ks * 32), a, 0, 0, 0);
    acc[sub] = a;
  }
  #pragma unroll
  for (int sub = 0; sub < 4; ++sub) {
    #pragma unroll
    for (int r = 0; r < 4; ++r) {
      int co = cow + lg * 4 + r;
      int n = n0 + sub * 16 + l15;
      float val = acc[sub][r] + bq[co];
      int hh = co >> 6, rr = co & 63;
      if (rr < KEY_DIM)
        qbuf[((b * HEADS + hh) * KEY_DIM + rr) * NPOS + n] = val;
      else if (rr < 2 * KEY_DIM)
        kbuf[((b * HEADS + hh) * KEY_DIM + (rr - KEY_DIM)) * NPOS + n] = val;
      else
        vb16[((size_t)(b * DIM + hh * HEAD_DIM + (rr - 2 * KEY_DIM))) * NPOS + n] = f2b(val);
    }
  }
}

// ---------------- kernel 2: L2-normalize q,k + emit bf16 transposed [bh][n][kk] ----------------
__global__ __launch_bounds__(256) void norm_kernel(
    const float* __restrict__ qbuf, const float* __restrict__ kbuf,
    unsigned short* __restrict__ qT16, unsigned short* __restrict__ kT16) {
  __shared__ float invn[16];
  __shared__ float tile[16][260];
  int bh = blockIdx.x;
  const float* src = blockIdx.y ? kbuf : qbuf;
  unsigned short* dst = blockIdx.y ? kT16 : qT16;
  const float* rows = src + (size_t)bh * 16 * NPOS;
  int t = threadIdx.x;
  int r = t >> 4, s = t & 15;
  float ss = 0.0f;
  for (int j = 0; j < 100; ++j) {
    float v = rows[r * NPOS + s + 16 * j];
    ss += v * v;
  }
  #pragma unroll
  for (int o = 8; o; o >>= 1) ss += __shfl_xor(ss, o, 64);
  if (s == 0) invn[r] = 1.0f / fmaxf(sqrtf(ss), 1e-12f);
  __syncthreads();
  float iv[16];
  #pragma unroll
  for (int kk = 0; kk < 16; ++kk) iv[kk] = invn[kk];
  for (int ch = 0; ch < 7; ++ch) {
    int m = ch * 256 + t;
    __syncthreads();
    if (m < NPOS)
      for (int kk = 0; kk < 16; ++kk) tile[kk][t] = rows[kk * NPOS + m];
    __syncthreads();
    if (m < NPOS) {
      short8 o0, o1;
      #pragma unroll
      for (int i = 0; i < 8; ++i) o0[i] = (short)f2b(tile[i][t] * iv[i]);
      #pragma unroll
      for (int i = 0; i < 8; ++i) o1[i] = (short)f2b(tile[8 + i][t] * iv[8 + i]);
      size_t base = ((size_t)bh * NPOS + m) * KEY_DIM;
      *(short8*)(dst + base) = o0;
      *(short8*)(dst + base + 8) = o1;
    }
  }
}

// ---------------- kernel 3: fused attention, MFMA, QBLK=16, 8 waves ----------------
__global__ __launch_bounds__(512) void attn_kernel(
    const unsigned short* __restrict__ qT16, const unsigned short* __restrict__ kT16,
    const unsigned short* __restrict__ vb16, const float* __restrict__ temp,
    const float* __restrict__ supp, const float* __restrict__ wpe,
    const float* __restrict__ bpe, unsigned short* __restrict__ ybT) {
  __shared__ __align__(128) unsigned short s16[QBLK * NPOS];  // 51200 B
  __shared__ unsigned hred[8][NBINS];                         // 8192 B (hist, then PV partials)
  __shared__ float invs[QBLK];
  int t = threadIdx.x, lane = t & 63, w = t >> 6;
  int l15 = lane & 15, lg = lane >> 4;
  int n0 = blockIdx.x * QBLK;
  int h = blockIdx.y, b = blockIdx.z;
  int bh = b * HEADS + h;
  float tscale = temp[h];
  float sgm = 1.0f / (1.0f + __expf(-supp[0]));

  // A-frag: Q tile (16 q-rows x K=32, kk>=16 zero via lanes>=32)
  {
    short8 qa = {0, 0, 0, 0, 0, 0, 0, 0};
    if (lane < 32)
      qa = *(const short8*)(qT16 + ((size_t)bh * NPOS + n0 + l15) * KEY_DIM + lg * 8);
    // ---- QK^T: 100 m-tiles across 8 waves ----
    for (int mt = w; mt < NPOS / 16; mt += 8) {
      int m0 = mt * 16;
      short8 kb = {0, 0, 0, 0, 0, 0, 0, 0};
      if (lane < 32)
        kb = *(const short8*)(kT16 + ((size_t)bh * NPOS + m0 + l15) * KEY_DIM + lg * 8);
      f32x4 acc = {0.f, 0.f, 0.f, 0.f};
      acc = __builtin_amdgcn_mfma_f32_16x16x32_bf16(qa, kb, acc, 0, 0, 0);
      #pragma unroll
      for (int r = 0; r < 4; ++r) {
        int row = lg * 4 + r;
        int byteoff = (row * 3200 + (m0 + l15) * 2) ^ smask(row);
        s16[byteoff >> 1] = f2b(acc[r] * tscale);
      }
    }
  }
  __syncthreads();

  // ---- per-wave select + softmax: wave w owns rows 2w, 2w+1 ----
  for (int rl = 0; rl < 2; ++rl) {
    int rr = w * 2 + rl;
    int rbase = rr * 3200, xr = smask(rr);
    float sv[25];
    float mn = 3.4e38f, mx = -3.4e38f;
    #pragma unroll
    for (int k = 0; k < 25; ++k) {
      int byteoff = rbase + (((lane + 64 * k) * 2) ^ xr);
      float v = b2f(s16[byteoff >> 1]);
      sv[k] = v; mn = fminf(mn, v); mx = fmaxf(mx, v);
    }
    ((uint4v*)hred[w])[lane] = (uint4v){0, 0, 0, 0};
    #pragma unroll
    for (int o = 32; o; o >>= 1) {
      mn = fminf(mn, __shfl_xor(mn, o, 64));
      mx = fmaxf(mx, __shfl_xor(mx, o, 64));
    }
    float range = fmaxf(mx - mn, 1e-30f) * 1.000001f;
    float invw = (float)NBINS / range;
    #pragma unroll
    for (int k = 0; k < 25; ++k) {
      int idx = (int)((sv[k] - mn) * invw);
      idx = idx < 0 ? 0 : (idx > NBINS - 1 ? NBINS - 1 : idx);
      atomicAdd(&hred[w][idx], 1u);
    }
    int h0 = (int)hred[w][4 * lane], h1 = (int)hred[w][4 * lane + 1];
    int h2 = (int)hred[w][4 * lane + 2], h3 = (int)hred[w][4 * lane + 3];
    int lsum = h0 + h1 + h2 + h3;
    int incl = lsum;
    #pragma unroll
    for (int o = 1; o < 64; o <<= 1) {
      int xx = __shfl_up(incl, o, 64);
      if (lane >= o) incl += xx;
    }
    int c = incl - lsum;
    int cand = 1 << 30;
    if (c <= RSEL && c + h0 > RSEL) cand = 4 * lane;
    c += h0; if (c <= RSEL && c + h1 > RSEL) cand = 4 * lane + 1;
    c += h1; if (c <= RSEL && c + h2 > RSEL) cand = 4 * lane + 2;
    c += h2; if (c <= RSEL && c + h3 > RSEL) cand = 4 * lane + 3;
    #pragma unroll
    for (int o = 32; o; o >>= 1) cand = min(cand, __shfl_xor(cand, o, 64));
    float thr = mn + (float)cand * (range / (float)NBINS);

    float lmax = -3.4e38f;
    #pragma unroll
    for (int k = 0; k < 25; ++k) {
      float p = sv[k] * (sv[k] >= thr ? 1.0f : sgm);
      sv[k] = p;
      lmax = fmaxf(lmax, p);
    }
    #pragma unroll
    for (int o = 32; o; o >>= 1) lmax = fmaxf(lmax, __shfl_xor(lmax, o, 64));
    float lsumf = 0.0f;
    #pragma unroll
    for (int k = 0; k < 25; ++k) {
      float e = __expf(sv[k] - lmax);
      lsumf += e;
      int byteoff = rbase + (((lane + 64 * k) * 2) ^ xr);
      s16[byteoff >> 1] = f2b(e);
    }
    #pragma unroll
    for (int o = 32; o; o >>= 1) lsumf += __shfl_xor(lsumf, o, 64);
    if (lane == 0) invs[rr] = 1.0f / lsumf;
  }
  __syncthreads();

  // ---- PV: wave w -> d-tile (w&1), m-residue (w>>1) mod 4 — no redundancy ----
  {
    float* red = (float*)hred[w];
    int tile = w & 1, d0 = tile * 16;
    const unsigned short* vrow = vb16 + ((size_t)(b * DIM + h * HEAD_DIM + d0 + l15)) * NPOS;
    f32x4 acc = {0.f, 0.f, 0.f, 0.f};
    for (int c = (w >> 1); c < NPOS / 32; c += 4) {
      int m0 = c * 32 + lg * 8;
      short8 va = *(const short8*)(vrow + m0);
      int byteoff = (l15 * 3200 + m0 * 2) ^ smask(l15);
      short8 pb = *(const short8*)(s16 + (byteoff >> 1));
      acc = __builtin_amdgcn_mfma_f32_16x16x32_bf16(va, pb, acc, 0, 0, 0);
    }
    #pragma unroll
    for (int r = 0; r < 4; ++r) red[(lg * 4 + r) * 16 + l15] = acc[r];
  }
  __syncthreads();

  // ---- epilogue: 4-way cross-wave reduce + normalize + fused pe conv + bf16 store ----
  {
    int tl = t >> 8, i = (t >> 4) & 15, j = t & 15;
    int p = i * 16 + j;
    float v = ((float*)hred[tl])[p] + ((float*)hred[tl + 2])[p] +
              ((float*)hred[tl + 4])[p] + ((float*)hred[tl + 6])[p];
    int c = h * HEAD_DIM + tl * 16 + i;
    int n = n0 + j;
    float o = v * invs[j];
    int py = n / 40, px = n - py * 40;
    const unsigned short* vp = vb16 + (size_t)(b * DIM + c) * NPOS;
    const float* w9 = wpe + c * 9;
    float acc2 = bpe[c];
    #pragma unroll
    for (int dy = -1; dy <= 1; ++dy) {
      int iy = py + dy;
      if (iy < 0 || iy > 39) continue;
      #pragma unroll
      for (int dx = -1; dx <= 1; ++dx) {
        int ix = px + dx;
        if (ix < 0 || ix > 39) continue;
        acc2 = fmaf(b2f(vp[iy * 40 + ix]), w9[(dy + 1) * 3 + (dx + 1)], acc2);
      }
    }
    o += acc2;
    ybT[((size_t)(b * NPOS + n)) * DIM + c] = f2b(o);
  }
}

// ---------------- kernel 5: proj via MFMA -> fp32 out ----------------
__global__ __launch_bounds__(256) void proj_mfma(
    const unsigned short* __restrict__ ybT, const unsigned short* __restrict__ wpb,
    const float* __restrict__ bp, float* __restrict__ out) {
  int t = threadIdx.x, lane = t & 63, w = t >> 6;
  int l15 = lane & 15, lg = lane >> 4;
  int n0 = blockIdx.x * 64, co0 = blockIdx.y * 64, b = blockIdx.z;
  int cow = co0 + w * 16;
  short8 af[8];
  #pragma unroll
  for (int ks = 0; ks < 8; ++ks)
    af[ks] = *(const short8*)(wpb + (size_t)(cow + l15) * DIM + ks * 32 + lg * 8);
  f32x4 acc[4];
  #pragma unroll
  for (int sub = 0; sub < 4; ++sub) {
    int n = n0 + sub * 16 + l15;
    const unsigned short* yb = ybT + (size_t)(b * NPOS + n) * DIM + lg * 8;
    f32x4 a = {0.f, 0.f, 0.f, 0.f};
    #pragma unroll
    for (int ks = 0; ks < 8; ++ks)
      a = __builtin_amdgcn_mfma_f32_16x16x32_bf16(af[ks], *(const short8*)(yb + ks * 32), a, 0, 0, 0);
    acc[sub] = a;
  }
  #pragma unroll
  for (int sub = 0; sub < 4; ++sub) {
    #pragma unroll
    for (int r = 0; r < 4; ++r) {
      int co = cow + lg * 4 + r;
      int n = n0 + sub * 16 + l15;
      out[((size_t)(b * DIM + co)) * NPOS + n] = acc[sub][r] + bp[co];
    }
  }
}

extern "C" void kernel_launch(void* const* d_in, const int* in_sizes, int n_in,
                              void* d_out, int out_size, void* d_ws, size_t ws_size,
                              hipStream_t stream) {
  (void)in_sizes; (void)n_in; (void)out_size; (void)ws_size;
  const float* x = (const float*)d_in[0];
  const float* w_qkv = (const float*)d_in[1];
  const float* b_qkv = (const float*)d_in[2];
  const float* w_proj = (const float*)d_in[3];
  const float* b_proj = (const float*)d_in[4];
  const float* w_pe = (const float*)d_in[5];
  const float* b_pe = (const float*)d_in[6];
  const float* temperature = (const float*)d_in[7];
  const float* supp = (const float*)d_in[8];

  float* wsf = (float*)d_ws;
  float* qbuf = wsf;                                    // 409600 f
  float* kbuf = qbuf + 409600;                          // 409600 f
  unsigned short* vb16 = (unsigned short*)(kbuf + 409600);  // 819200 bf16
  unsigned short* qT16 = vb16 + 819200;                 // 409600
  unsigned short* kT16 = qT16 + 409600;                 // 409600
  unsigned short* xT16 = kT16 + 409600;                 // 819200
  unsigned short* ybT  = xT16 + 819200;                 // 819200
  unsigned short* wqb  = ybT + 819200;                  // 131072
  unsigned short* wpb  = wqb + 131072;                  // 65536
  float* out = (float*)d_out;

  xpose_kernel<<<dim3(25, 4, 2), 256, 0, stream>>>(x, xT16);
  convw_kernel<<<dim3(96, 1, 1), 256, 0, stream>>>(w_qkv, w_proj, wqb, wpb);
  qkv_mfma<<<dim3(25, 8, 2), 256, 0, stream>>>(xT16, wqb, b_qkv, qbuf, kbuf, vb16);
  norm_kernel<<<dim3(16, 2), 256, 0, stream>>>(qbuf, kbuf, qT16, kT16);
  attn_kernel<<<dim3(NPOS / QBLK, HEADS, 2), 512, 0, stream>>>(qT16, kT16, vb16, temperature, supp, w_pe, b_pe, ybT);
  proj_mfma<<<dim3(25, 4, 2), 256, 0, stream>>>(ybT, wpb, b_proj, out);
}